// Round 13
// baseline (109.963 us; speedup 1.0000x reference)
//
#include <hip/hip_runtime.h>
#include <hip/hip_bf16.h>
#include <stdint.h>

// Problem constants
#define E_    8
#define K_    2048
#define N_    2048
#define T_    1024
#define TOPK_ 2
#define NG_   16      // K/GROUP_SIZE
#define MAXM  512

// GEMM tile: 64m x 128n x 32k, 4 waves, KSPLIT=2
#define BM 64
#define BN 128
#define BK 32
#define KSPLIT 2
#define KCHUNK (K_ / KSPLIT)     // 1024
#define NST (KCHUNK / BK)        // 32 steps
#define BSTRIDE 132              // padded B-row stride in u16 (264 B)

typedef __attribute__((ext_vector_type(8))) short bf16x8;
typedef __attribute__((ext_vector_type(4))) float f32x4;
typedef __attribute__((ext_vector_type(4))) int i32x4;
typedef __attribute__((ext_vector_type(2))) unsigned int u32x2;
typedef __attribute__((ext_vector_type(4))) unsigned int u32x4;
typedef __attribute__((ext_vector_type(8))) unsigned short u16x8;

__device__ __forceinline__ unsigned short f2bf_rne(float f) {
    unsigned u = __float_as_uint(f);
    u += 0x7fffu + ((u >> 16) & 1u);
    return (unsigned short)(u >> 16);
}
// exact pack for ints 0..255
__device__ __forceinline__ unsigned pack2bf(int lo, int hi) {
    float fl = (float)lo, fh = (float)hi;
    return (__float_as_uint(fl) >> 16) | (__float_as_uint(fh) & 0xffff0000u);
}

__device__ __forceinline__ void gload_lds16(const void* g, void* l) {
    __builtin_amdgcn_global_load_lds(
        (__attribute__((address_space(1))) unsigned int*)g,
        (__attribute__((address_space(3))) unsigned int*)l,
        16, 0, 0);
}

// ---------------- kernel 1: extract diagonal scales/zeros -------------------
__global__ void prep_sz(const float* __restrict__ scales, const float* __restrict__ zeros,
                        float* __restrict__ sd, float* __restrict__ zd, int* __restrict__ cnt)
{
    int i = blockIdx.x * 256 + threadIdx.x;      // over E*K = 16384
    int e = i >> 11;
    int k = i & (K_ - 1);
    int g = k >> 7;
    size_t src = ((size_t)e * K_ + k) * NG_ + g;
    sd[i] = scales[src];
    zd[i] = zeros[src];
    if (i < E_) cnt[i] = 0;
}

// ---------------- kernel 2: route pairs -------------------------------------
__global__ void route_k(const int* __restrict__ topk_ids, int* __restrict__ cnt,
                        int* __restrict__ ptj)
{
    int idx = blockIdx.x * 256 + threadIdx.x;
    if (idx < T_ * TOPK_) {
        int e = topk_ids[idx];
        int slot = atomicAdd(&cnt[e], 1);
        if (slot < T_ * TOPK_) ptj[e * (T_ * TOPK_) + slot] = idx;
    }
}

// ---------------- kernel 3: aprep + fused zdot (proven R12) -----------------
__global__ void aprep_k(const float* __restrict__ x, const float* __restrict__ sdiag,
                        const float* __restrict__ zdiag,
                        const int* __restrict__ cnt, const int* __restrict__ ptj,
                        unsigned short* __restrict__ apack, float* __restrict__ zdot)
{
    int e = blockIdx.y;
    int slot = blockIdx.x;
    if (slot >= min(cnt[e], MAXM)) return;
    int tj = ptj[e * (T_ * TOPK_) + slot];
    int t = tj >> 1;
    const float* xr = x + (size_t)t * K_;
    const float* sr = sdiag + (size_t)e * K_;
    const float* zr = zdiag + (size_t)e * K_;
    int k = threadIdx.x * 8;
    f32x4 a0 = *(const f32x4*)(xr + k);
    f32x4 s0 = *(const f32x4*)(sr + k);
    f32x4 a1 = *(const f32x4*)(xr + k + 4);
    f32x4 s1 = *(const f32x4*)(sr + k + 4);
    f32x4 z0 = *(const f32x4*)(zr + k);
    f32x4 z1 = *(const f32x4*)(zr + k + 4);
    u16x8 h;
    h[0] = f2bf_rne(a0.x * s0.x);
    h[1] = f2bf_rne(a0.y * s0.y);
    h[2] = f2bf_rne(a0.z * s0.z);
    h[3] = f2bf_rne(a0.w * s0.w);
    h[4] = f2bf_rne(a1.x * s1.x);
    h[5] = f2bf_rne(a1.y * s1.y);
    h[6] = f2bf_rne(a1.z * s1.z);
    h[7] = f2bf_rne(a1.w * s1.w);
    *(u16x8*)(apack + ((size_t)e * MAXM + slot) * K_ + k) = h;
    float zp = a0.x * z0.x + a0.y * z0.y + a0.z * z0.z + a0.w * z0.w
             + a1.x * z1.x + a1.y * z1.y + a1.z * z1.z + a1.w * z1.w;
#pragma unroll
    for (int off = 32; off > 0; off >>= 1) zp += __shfl_down(zp, off);
    __shared__ float red[4];
    int lane = threadIdx.x & 63;
    int w = threadIdx.x >> 6;
    if (lane == 0) red[w] = zp;
    __syncthreads();
    if (threadIdx.x == 0)
        zdot[tj] = red[0] + red[1] + red[2] + red[3];
}

// ---------------- kernel 4: per-expert GEMM ---------------------------------
// 64x128x32 tile, 4 waves (2m x 2n, each 32m x 64n), KSPLIT=2 -> 1024 live
// blocks, 25 KB LDS, ~4 blocks/CU. B read ROW-major from wq: per wave-instr
// two contiguous 512 B runs (lanes span 2 k-rows x 128 n) -> large DRAM
// granules (the theory: 256 B column reads capped HBM at 1.7 TB/s).
// B transposed via padded [32][132] u16 LDS; frags = 8x ds_read_u16 (R9's
// proven-correct path). A: 1 global_load_lds/wave, source chunk-swizzle.
// Schedule: R6's counted-vmcnt discipline (wait leaves next-next B in flight).
__global__ __launch_bounds__(256, 4)
void moe_gemm(const int* __restrict__ wq, const unsigned short* __restrict__ apack,
              const float* __restrict__ topk_w, const int* __restrict__ cnt,
              const int* __restrict__ ptj, const float* __restrict__ zdot,
              float* __restrict__ part, float* __restrict__ out, int use_part)
{
    int bz = blockIdx.z;
    int e = bz >> 1;
    int ks = bz & 1;
    int k0 = ks * KCHUNK;
    int count = min(cnt[e], MAXM);
    int m0 = blockIdx.y * BM;
    if (m0 >= count) return;
    int n0 = blockIdx.x * BN;

    __shared__ alignas(16) unsigned short As[2][BM * BK];       // 2 x 4 KB
    __shared__ alignas(16) unsigned short Bs[2][BK * BSTRIDE];  // 2 x 8.25 KB

    int tid = threadIdx.x;
    int lane = tid & 63;
    int wid = tid >> 6;
    int wm = (wid >> 1) * 32;                     // 0,32
    int wn = (wid & 1) * 64;                      // 0,64

    // A staging: 1 gload_lds/wave; lane l -> row wid*16 + (l>>2), phys chunk l&3.
    // Source pre-swizzled so phys chunk p holds logical chunk p^(row&3).
    int arow_l = (lane >> 2);                     // 0..15 within wave
    int arow = wid * 16 + arow_l;
    int achk = (lane & 3) ^ (arow & 3);           // logical k-chunk at source
    const char* ag = (const char*)(apack + (size_t)e * MAXM * K_)
                   + ((size_t)(m0 + arow) * K_) * 2 + achk * 16;

    // B staging: thread -> base k-row r0 = tid>>5 (0..7), cols c..c+3 (c = (tid&31)*4)
    int b_r0 = tid >> 5;
    int b_c = (tid & 31) * 4;
    const int* brow = wq + (size_t)e * K_ * N_ + n0 + b_c;

    f32x4 acc[2][4] = {};
    i32x4 b0[4], b1[4], b2[4];                    // 3 B reg sets (static idx)

    auto stageA = [&](int buf, int kt) {
        const char* g = ag + (size_t)(k0 + kt * BK) * 2;
        gload_lds16(g, (char*)As[buf] + wid * 1024);
    };
    auto loadB = [&](i32x4* br, int kt) {
        const int* base = brow + (size_t)(k0 + kt * BK + b_r0) * N_;
#pragma unroll
        for (int i = 0; i < 4; ++i)
            br[i] = *(const i32x4*)(base + (size_t)(i * 8) * N_);
    };
    auto packB = [&](const i32x4* br, int bbuf) {
#pragma unroll
        for (int i = 0; i < 4; ++i) {
            int row = b_r0 + i * 8;
            i32x4 v = br[i];
            u32x2 h = { pack2bf(v.x, v.y), pack2bf(v.z, v.w) };
            *(u32x2*)(&Bs[bbuf][row * BSTRIDE + b_c]) = h;
        }
    };
    auto comp = [&](int buf) {
        // A frags: 2 x ds_read_b128 (chunk-swizzled)
        bf16x8 af[2];
#pragma unroll
        for (int mi = 0; mi < 2; ++mi) {
            int row = wm + mi * 16 + (lane & 15);
            int kc = (lane >> 4) ^ (row & 3);
            af[mi] = *(const bf16x8*)((const char*)As[buf] + row * 64 + kc * 16);
        }
        // B frags: 8 x ds_read_u16 each (k = (lane>>4)*8 + j, col n)
        bf16x8 bfr[4];
#pragma unroll
        for (int ni = 0; ni < 4; ++ni) {
            int ncol = wn + ni * 16 + (lane & 15);
            const unsigned short* bp = &Bs[buf][((lane >> 4) * 8) * BSTRIDE + ncol];
            unsigned d0 = (unsigned)bp[0]           | ((unsigned)bp[BSTRIDE]     << 16);
            unsigned d1 = (unsigned)bp[2 * BSTRIDE] | ((unsigned)bp[3 * BSTRIDE] << 16);
            unsigned d2 = (unsigned)bp[4 * BSTRIDE] | ((unsigned)bp[5 * BSTRIDE] << 16);
            unsigned d3 = (unsigned)bp[6 * BSTRIDE] | ((unsigned)bp[7 * BSTRIDE] << 16);
            union { unsigned u[4]; bf16x8 v; } f = {{ d0, d1, d2, d3 }};
            bfr[ni] = f.v;
        }
#pragma unroll
        for (int mi = 0; mi < 2; ++mi)
#pragma unroll
            for (int ni = 0; ni < 4; ++ni)
                acc[mi][ni] = __builtin_amdgcn_mfma_f32_16x16x32_bf16(
                    af[mi], bfr[ni], acc[mi][ni], 0, 0, 0);
    };

    // ---- prologue: A0 staged; B tiles 0,1,2 in flight; pack tile 0 ----
    stageA(0, 0);                                  // 1 vmem (oldest)
    __builtin_amdgcn_sched_barrier(0);
    loadB(b0, 0);                                  // +4
    loadB(b1, 1);                                  // +4
    loadB(b2, 2);                                  // +4
    packB(b0, 0);                                  // implicit wait drains A0+b0
    asm volatile("s_waitcnt vmcnt(8) lgkmcnt(0)" ::: "memory");  // b1,b2 in flight
    __builtin_amdgcn_s_barrier();
    __builtin_amdgcn_sched_barrier(0);

    int kt = 0;
    // step kt: stage A(kt+1)[1, oldest], load B(kt+3)[4], compute tile kt,
    // pack tile kt+1 (regs loaded at kt-2, already retired). vmcnt(4) drains
    // B(kt+2)+A(kt+1), keeps B(kt+3) in flight across the barrier.
#define STEP(C, BL, BP) do {                                                  \
        stageA(C ^ 1, kt + 1);                                                \
        __builtin_amdgcn_sched_barrier(0);                                    \
        loadB(BL, kt + 3);                                                    \
        comp(C);                                                              \
        packB(BP, C ^ 1);                                                     \
        asm volatile("s_waitcnt vmcnt(4) lgkmcnt(0)" ::: "memory");           \
        __builtin_amdgcn_s_barrier();                                         \
        __builtin_amdgcn_sched_barrier(0);                                    \
        ++kt;                                                                 \
    } while (0)

#pragma unroll 1
    for (int it = 0; it < 4; ++it) {              // steps 0..23 (period 6)
        STEP(0, b0, b1);
        STEP(1, b1, b2);
        STEP(0, b2, b0);
        STEP(1, b0, b1);
        STEP(0, b1, b2);
        STEP(1, b2, b0);
    }
    STEP(0, b0, b1);                               // 24
    STEP(1, b1, b2);                               // 25
    STEP(0, b2, b0);                               // 26  loads t29 -> b2
    STEP(1, b0, b1);                               // 27  loads t30 -> b0
    STEP(0, b1, b2);                               // 28  loads t31 -> b1
#undef STEP
    // ---- tail: steps 29,30 (no more loads), 31 ----
    stageA(0, 30);
    __builtin_amdgcn_sched_barrier(0);
    comp(1);                                       // tile 29
    packB(b0, 0);                                  // tile 30
    asm volatile("s_waitcnt vmcnt(0) lgkmcnt(0)" ::: "memory");
    __builtin_amdgcn_s_barrier();
    __builtin_amdgcn_sched_barrier(0);
    stageA(1, 31);
    __builtin_amdgcn_sched_barrier(0);
    comp(0);                                       // tile 30
    packB(b1, 1);                                  // tile 31
    asm volatile("s_waitcnt vmcnt(0) lgkmcnt(0)" ::: "memory");
    __builtin_amdgcn_s_barrier();
    __builtin_amdgcn_sched_barrier(0);
    comp(1);                                       // tile 31

    // ---- epilogue: part[(tj*2+ks)][n] = w*(acc + zdot_once) ----
#pragma unroll
    for (int mi = 0; mi < 2; ++mi) {
        int prow = m0 + wm + mi * 16 + ((lane >> 4) << 2);
#pragma unroll
        for (int r = 0; r < 4; ++r) {
            int p = prow + r;
            if (p < count) {
                int tj = ptj[e * (T_ * TOPK_) + p];
                float w = topk_w[tj];
                float zdv = ks ? 0.f : zdot[tj];
#pragma unroll
                for (int ni = 0; ni < 4; ++ni) {
                    float v = w * (acc[mi][ni][r] + zdv);
                    int col = n0 + wn + ni * 16 + (lane & 15);
                    if (use_part)
                        part[((size_t)tj * 2 + ks) * N_ + col] = v;
                    else
                        atomicAdd(out + (size_t)(tj >> 1) * N_ + col, v);
                }
            }
        }
    }
}

// ---------------- kernel 5: out[t] = sum of part rows 4t..4t+3 --------------
__global__ void reduce_k(const float* __restrict__ part, float* __restrict__ out)
{
    int g = blockIdx.x * 256 + threadIdx.x;       // over T*N/4
    int t = g >> 9;                                // 512 f32x4 per row
    int nc = g & 511;
    const f32x4* p = (const f32x4*)part;
    size_t base = ((size_t)t * 4) << 9;
    f32x4 s = p[base + nc] + p[base + 512 + nc] + p[base + 1024 + nc] + p[base + 1536 + nc];
    ((f32x4*)out)[g] = s;
}

// ---------------- launch -----------------------------------------------------
extern "C" void kernel_launch(void* const* d_in, const int* in_sizes, int n_in,
                              void* d_out, int out_size, void* d_ws, size_t ws_size,
                              hipStream_t stream)
{
    const float* x       = (const float*)d_in[0];
    const int*   wq      = (const int*)d_in[1];
    const float* scales  = (const float*)d_in[2];
    const float* zeros   = (const float*)d_in[3];
    const float* topk_w  = (const float*)d_in[4];
    const int*   topk_id = (const int*)d_in[5];
    float* out = (float*)d_out;

    char* ws = (char*)d_ws;
    float* sdiag = (float*)(ws + 0);                    //  64 KB
    float* zdiag = (float*)(ws + 65536);                //  64 KB
    int*   cnt   = (int*)(ws + 131072);                 //  4 KB
    int*   ptj   = (int*)(ws + 135168);                 //  64 KB
    float* zdot  = (float*)(ws + 200704);               //  8 KB
    unsigned short* apack = (unsigned short*)(ws + (1 << 20));   // 16 MB
    float* part  = (float*)(ws + ((size_t)17 << 20));            // 33.6 MB (2048*2 x 2048 f32)
    size_t need = ((size_t)17 << 20) + (size_t)T_ * TOPK_ * KSPLIT * N_ * sizeof(float);
    int use_part = (ws_size >= need) ? 1 : 0;

    prep_sz<<<E_ * K_ / 256, 256, 0, stream>>>(scales, zeros, sdiag, zdiag, cnt);
    route_k<<<T_ * TOPK_ / 256, 256, 0, stream>>>(topk_id, cnt, ptj);
    aprep_k<<<dim3(MAXM, E_), 256, 0, stream>>>(x, sdiag, zdiag, cnt, ptj, apack, zdot);
    if (!use_part)
        hipMemsetAsync(d_out, 0, (size_t)T_ * N_ * sizeof(float), stream);
    moe_gemm<<<dim3(N_ / BN, MAXM / BM, E_ * KSPLIT), 256, 0, stream>>>(
        wq, apack, topk_w, cnt, ptj, zdot, part, out, use_part);
    if (use_part)
        reduce_k<<<T_ * N_ / 4 / 256, 256, 0, stream>>>(part, out);
}

// Round 14
// 85.446 us; speedup vs baseline: 1.2869x; 1.2869x over previous
//
#include <hip/hip_runtime.h>
#include <hip/hip_bf16.h>
#include <stdint.h>

// Problem constants
#define E_    8
#define K_    2048
#define N_    2048
#define T_    1024
#define TOPK_ 2
#define NG_   16      // K/GROUP_SIZE
#define MAXM  512     // per-expert pair capacity (mean 256, sd~15 -> +17 sigma)

// GEMM tile (R6 winner geometry)
#define BM 128
#define BN 64
#define BK 64
#define NST (K_ / BK)        // 32 K-steps
#define MTILES (MAXM / BM)   // 4

typedef __attribute__((ext_vector_type(8))) short bf16x8;
typedef __attribute__((ext_vector_type(4))) float f32x4;
typedef __attribute__((ext_vector_type(4))) unsigned int u32x4;
typedef __attribute__((ext_vector_type(8))) unsigned short u16x8;

__device__ __forceinline__ unsigned short f2bf_rne(float f) {
    unsigned u = __float_as_uint(f);
    u += 0x7fffu + ((u >> 16) & 1u);
    return (unsigned short)(u >> 16);
}
// exact for floats whose low 16 mantissa bits are zero (ints 0..255)
__device__ __forceinline__ unsigned short f2bf_trunc(float f) {
    return (unsigned short)(__float_as_uint(f) >> 16);
}

__device__ __forceinline__ void gload_lds16(const void* g, void* l) {
    __builtin_amdgcn_global_load_lds(
        (__attribute__((address_space(1))) unsigned int*)g,
        (__attribute__((address_space(3))) unsigned int*)l,
        16, 0, 0);
}

// ---------------- kernel 1: extract diagonal scales/zeros, zero counters ----
__global__ void prep_sz(const float* __restrict__ scales, const float* __restrict__ zeros,
                        float* __restrict__ sd, float* __restrict__ zd, int* __restrict__ cnt)
{
    int i = blockIdx.x * 256 + threadIdx.x;      // over E*K = 16384
    int e = i >> 11;
    int k = i & (K_ - 1);
    int g = k >> 7;
    size_t src = ((size_t)e * K_ + k) * NG_ + g;
    sd[i] = scales[src];
    zd[i] = zeros[src];
    if (i < E_) cnt[i] = 0;
}

// ---------------- kernel 2: route pairs (t,j) -> per-expert compact lists ---
__global__ void route_k(const int* __restrict__ topk_ids, int* __restrict__ cnt,
                        int* __restrict__ ptj)
{
    int idx = blockIdx.x * 256 + threadIdx.x;    // grid 8 x 256 = 2048
    if (idx < T_ * TOPK_) {
        int e = topk_ids[idx];
        int slot = atomicAdd(&cnt[e], 1);
        if (slot < T_ * TOPK_) ptj[e * (T_ * TOPK_) + slot] = idx;
    }
}

// ---------------- kernel 3: aprep + fused zdot (proven R12/R13) -------------
// A[e][slot][k] = bf16(x[t,k]*s[e,k]);  zdot[tj] = dot(x[t], z_diag[e]).
__global__ void aprep_k(const float* __restrict__ x, const float* __restrict__ sdiag,
                        const float* __restrict__ zdiag,
                        const int* __restrict__ cnt, const int* __restrict__ ptj,
                        unsigned short* __restrict__ apack, float* __restrict__ zdot)
{
    int e = blockIdx.y;
    int slot = blockIdx.x;
    if (slot >= min(cnt[e], MAXM)) return;
    int tj = ptj[e * (T_ * TOPK_) + slot];
    int t = tj >> 1;
    const float* xr = x + (size_t)t * K_;
    const float* sr = sdiag + (size_t)e * K_;
    const float* zr = zdiag + (size_t)e * K_;
    int k = threadIdx.x * 8;
    f32x4 a0 = *(const f32x4*)(xr + k);
    f32x4 s0 = *(const f32x4*)(sr + k);
    f32x4 a1 = *(const f32x4*)(xr + k + 4);
    f32x4 s1 = *(const f32x4*)(sr + k + 4);
    f32x4 z0 = *(const f32x4*)(zr + k);
    f32x4 z1 = *(const f32x4*)(zr + k + 4);
    u16x8 h;
    h[0] = f2bf_rne(a0.x * s0.x);
    h[1] = f2bf_rne(a0.y * s0.y);
    h[2] = f2bf_rne(a0.z * s0.z);
    h[3] = f2bf_rne(a0.w * s0.w);
    h[4] = f2bf_rne(a1.x * s1.x);
    h[5] = f2bf_rne(a1.y * s1.y);
    h[6] = f2bf_rne(a1.z * s1.z);
    h[7] = f2bf_rne(a1.w * s1.w);
    *(u16x8*)(apack + ((size_t)e * MAXM + slot) * K_ + k) = h;
    // fused zdot
    float zp = a0.x * z0.x + a0.y * z0.y + a0.z * z0.z + a0.w * z0.w
             + a1.x * z1.x + a1.y * z1.y + a1.z * z1.z + a1.w * z1.w;
#pragma unroll
    for (int off = 32; off > 0; off >>= 1) zp += __shfl_down(zp, off);
    __shared__ float red[4];
    int lane = threadIdx.x & 63;
    int w = threadIdx.x >> 6;
    if (lane == 0) red[w] = zp;
    __syncthreads();
    if (threadIdx.x == 0)
        zdot[tj] = red[0] + red[1] + red[2] + red[3];
}

// ---------------- kernel 4: per-expert GEMM (R6 winner, atomic epilogue) ----
// 128x64 tile, BK=64, 32 K-steps. 3 named B reg sets (depth-2 issue), A via
// global_load_lds depth-1, counted vmcnt at the barrier. This gemm is
// feed-rate-bound: wq column reads (256B granules at 8KB stride) stream at
// ~1.7 TB/s on this part — measured invariant across schedules (R2-R13).
__global__ __launch_bounds__(256, 3)
void moe_gemm(const int* __restrict__ wq, const unsigned short* __restrict__ apack,
              const float* __restrict__ topk_w, const int* __restrict__ cnt,
              const int* __restrict__ ptj, const float* __restrict__ zdot,
              float* __restrict__ out)
{
    int e = blockIdx.z;
    int count = min(cnt[e], MAXM);
    int m0 = blockIdx.y * BM;
    if (m0 >= count) return;                      // early-exit empty M-tiles
    int n0 = blockIdx.x * BN;

    __shared__ alignas(16) unsigned short As[2][BM * BK];   // 2 x 16 KB
    __shared__ alignas(16) unsigned short Bs[2][BN * BK];   // 2 x  8 KB

    int tid = threadIdx.x;
    int lane = tid & 63;
    int wid = tid >> 6;
    int wm = (wid >> 1) * 64;                     // wave tile 64m x 32n
    int wn = (wid & 1) * 32;

    // A staging geometry (per wave: 4 chunks of 8 rows, 1 KB each)
    int lrow = lane >> 3;
    int lcol = lane & 7;
    int aswz = (lcol ^ lrow) << 4;                // source-side swizzle
    const char* abase = (const char*)(apack + (size_t)e * MAXM * K_);

    // B staging: thread -> (n = tid&63, k-set = wave id, 16 k each)
    int b_n = tid & 63;
    int b_set = tid >> 6;
    const int* wcol = wq + (size_t)e * K_ * N_ + n0 + b_n;
    int bswz = (b_n & 7) << 4;

    f32x4 acc[4][2] = {};
    int b0[16], b1[16], b2[16];                   // 3 B prefetch sets (static idx)

    auto stageA = [&](int buf, int kt) {
        int kk = kt * BK;
#pragma unroll
        for (int ci = 0; ci < 4; ++ci) {
            int c = wid * 4 + ci;
            int p = m0 + c * 8 + lrow;
            const char* g = abase + ((size_t)p * K_ + kk) * 2 + aswz;
            gload_lds16(g, (char*)As[buf] + c * 1024);
        }
    };
    auto loadB = [&](int* br, int kt) {
        int kb = kt * BK + b_set * 16;
#pragma unroll
        for (int i = 0; i < 16; ++i)
            br[i] = wcol[(kb + i) * N_];
    };
    auto packB = [&](const int* br, int buf) {
        unsigned pk[8];
#pragma unroll
        for (int i = 0; i < 8; ++i) {
            unsigned lo = f2bf_trunc((float)br[2 * i]);
            unsigned hi = f2bf_trunc((float)br[2 * i + 1]);
            pk[i] = lo | (hi << 16);
        }
        char* bsrow = (char*)Bs[buf] + b_n * (BK * 2);
#pragma unroll
        for (int seg = 0; seg < 2; ++seg) {
            int kbyte = b_set * 32 + seg * 16;
            u32x4 v = { pk[seg * 4], pk[seg * 4 + 1], pk[seg * 4 + 2], pk[seg * 4 + 3] };
            *(u32x4*)(bsrow + (kbyte ^ bswz)) = v;
        }
    };
    auto comp = [&](int buf) {
#pragma unroll
        for (int kk2 = 0; kk2 < 2; ++kk2) {
            int kb = kk2 * 64 + ((lane >> 4) << 4);
            bf16x8 af[4], bfr[2];
#pragma unroll
            for (int mi = 0; mi < 4; ++mi) {
                int row = wm + mi * 16 + (lane & 15);
                af[mi] = *(const bf16x8*)((const char*)As[buf] + row * 128 + (kb ^ ((row & 7) << 4)));
            }
#pragma unroll
            for (int ni = 0; ni < 2; ++ni) {
                int row = wn + ni * 16 + (lane & 15);
                bfr[ni] = *(const bf16x8*)((const char*)Bs[buf] + row * 128 + (kb ^ ((row & 7) << 4)));
            }
#pragma unroll
            for (int mi = 0; mi < 4; ++mi)
#pragma unroll
                for (int ni = 0; ni < 2; ++ni)
                    acc[mi][ni] = __builtin_amdgcn_mfma_f32_16x16x32_bf16(
                        af[mi], bfr[ni], acc[mi][ni], 0, 0, 0);
        }
    };

    // ---- prologue: A0 staged; B tiles 0,1,2 in flight; pack tile 0 ----
    stageA(0, 0);                                  // 4 vmem (oldest)
    __builtin_amdgcn_sched_barrier(0);
    loadB(b0, 0);                                  // +16
    loadB(b1, 1);                                  // +16
    loadB(b2, 2);                                  // +16
    packB(b0, 0);                                  // implicit wait drains A0+b0
    asm volatile("s_waitcnt vmcnt(32) lgkmcnt(0)" ::: "memory");  // b1,b2 in flight
    __builtin_amdgcn_s_barrier();
    __builtin_amdgcn_sched_barrier(0);

    int kt = 0;
    // step kt: stage A(kt+1) [4, oldest], load B(kt+3) [16], compute tile kt,
    // pack tile kt+1 (loaded at step kt-2), wait vmcnt(16).
#define STEP(C, BL, BP) do {                                                  \
        stageA(C ^ 1, kt + 1);                                                \
        __builtin_amdgcn_sched_barrier(0);                                    \
        loadB(BL, kt + 3);                                                    \
        comp(C);                                                              \
        packB(BP, C ^ 1);                                                     \
        asm volatile("s_waitcnt vmcnt(16) lgkmcnt(0)" ::: "memory");          \
        __builtin_amdgcn_s_barrier();                                         \
        __builtin_amdgcn_sched_barrier(0);                                    \
        ++kt;                                                                 \
    } while (0)

#pragma unroll 1
    for (int it = 0; it < 4; ++it) {              // steps 0..23
        STEP(0, b0, b1);
        STEP(1, b1, b2);
        STEP(0, b2, b0);
        STEP(1, b0, b1);
        STEP(0, b1, b2);
        STEP(1, b2, b0);
    }
    STEP(0, b0, b1);                               // 24
    STEP(1, b1, b2);                               // 25
    STEP(0, b2, b0);                               // 26
    STEP(1, b0, b1);                               // 27
    STEP(0, b1, b2);                               // 28  (loads tile 31 -> b1)
#undef STEP
    // ---- tail: steps 29,30 (no more B loads), 31 ----
    stageA(0, 30);
    __builtin_amdgcn_sched_barrier(0);
    comp(1);
    packB(b0, 0);                                  // tile 30 (slot 30%3=0)
    asm volatile("s_waitcnt vmcnt(0) lgkmcnt(0)" ::: "memory");
    __builtin_amdgcn_s_barrier();
    __builtin_amdgcn_sched_barrier(0);
    stageA(1, 31);
    __builtin_amdgcn_sched_barrier(0);
    comp(0);
    packB(b1, 1);                                  // tile 31 (slot 31%3=1)
    asm volatile("s_waitcnt vmcnt(0) lgkmcnt(0)" ::: "memory");
    __builtin_amdgcn_s_barrier();
    __builtin_amdgcn_sched_barrier(0);
    comp(1);

    // ---- epilogue: out[t, n] += w*(acc + zdot)  (atomic, proven R2-R7) ----
#pragma unroll
    for (int mi = 0; mi < 4; ++mi) {
        int prow = m0 + wm + mi * 16 + ((lane >> 4) << 2);
#pragma unroll
        for (int r = 0; r < 4; ++r) {
            int p = prow + r;
            if (p < count) {
                int tj = ptj[e * (T_ * TOPK_) + p];
                float w = topk_w[tj];
                float zdv = zdot[tj];
                float* orow = out + (size_t)(tj >> 1) * N_ + n0 + wn + (lane & 15);
                atomicAdd(orow + 0,  w * (acc[mi][0][r] + zdv));
                atomicAdd(orow + 16, w * (acc[mi][1][r] + zdv));
            }
        }
    }
}

// ---------------- launch -----------------------------------------------------
extern "C" void kernel_launch(void* const* d_in, const int* in_sizes, int n_in,
                              void* d_out, int out_size, void* d_ws, size_t ws_size,
                              hipStream_t stream)
{
    const float* x       = (const float*)d_in[0];
    const int*   wq      = (const int*)d_in[1];
    const float* scales  = (const float*)d_in[2];
    const float* zeros   = (const float*)d_in[3];
    const float* topk_w  = (const float*)d_in[4];
    const int*   topk_id = (const int*)d_in[5];
    float* out = (float*)d_out;

    char* ws = (char*)d_ws;
    float* sdiag = (float*)(ws + 0);                    //  64 KB
    float* zdiag = (float*)(ws + 65536);                //  64 KB
    int*   cnt   = (int*)(ws + 131072);                 //  4 KB
    int*   ptj   = (int*)(ws + 135168);                 //  64 KB
    float* zdot  = (float*)(ws + 200704);               //  8 KB
    unsigned short* apack = (unsigned short*)(ws + (1 << 20));   // 16 MB

    prep_sz<<<E_ * K_ / 256, 256, 0, stream>>>(scales, zeros, sdiag, zdiag, cnt);
    route_k<<<T_ * TOPK_ / 256, 256, 0, stream>>>(topk_id, cnt, ptj);
    aprep_k<<<dim3(MAXM, E_), 256, 0, stream>>>(x, sdiag, zdiag, cnt, ptj, apack, zdot);
    hipMemsetAsync(d_out, 0, (size_t)T_ * N_ * sizeof(float), stream);
    moe_gemm<<<dim3(N_ / BN, MTILES, E_), 256, 0, stream>>>(
        wq, apack, topk_w, cnt, ptj, zdot, out);
}